// Round 9
// baseline (133.714 us; speedup 1.0000x reference)
//
#include <hip/hip_runtime.h>
#include <stdint.h>

#define DIM 256
#define NR 8192

typedef __bf16 bf16x8 __attribute__((ext_vector_type(8)));
typedef float  f32x16 __attribute__((ext_vector_type(16)));
typedef float  f32x4  __attribute__((ext_vector_type(4)));

#define WAITV(N) asm volatile("s_waitcnt vmcnt(" #N ")" ::: "memory")
#define GLDS(src, dst, sz) __builtin_amdgcn_global_load_lds( \
    (const __attribute__((address_space(1))) void*)(src),    \
    (__attribute__((address_space(3))) void*)(dst), sz, 0, 0)

__device__ __forceinline__ unsigned short f2bf_rne(float f) {
    unsigned int u = __float_as_uint(f);
    u += 0x7FFFu + ((u >> 16) & 1u);
    return (unsigned short)(u >> 16);
}

// One wave per row: f32 row -> bf16 + ||row||^2. Blocks [0,2048)->a, rest->b.
__global__ void prep_kernel(const float* __restrict__ a,
                            const float* __restrict__ b,
                            unsigned short* __restrict__ aB,
                            unsigned short* __restrict__ bB,
                            float* __restrict__ na,
                            float* __restrict__ nb) {
    const int w = threadIdx.x >> 6;
    const int l = threadIdx.x & 63;
    const int blk = blockIdx.x;
    const float* src; unsigned short* dst; float* nrm; int row;
    if (blk < 2048) { src = a; dst = aB; nrm = na; row = blk * 4 + w; }
    else            { src = b; dst = bB; nrm = nb; row = (blk - 2048) * 4 + w; }
    const float4 v = reinterpret_cast<const float4*>(src + (size_t)row * DIM)[l];
    float ss = v.x * v.x + v.y * v.y + v.z * v.z + v.w * v.w;
#pragma unroll
    for (int off = 32; off > 0; off >>= 1) ss += __shfl_down(ss, off);
    if (l == 0) nrm[row] = ss;
    ushort4 o = make_ushort4(f2bf_rne(v.x), f2bf_rne(v.y), f2bf_rne(v.z), f2bf_rne(v.w));
    reinterpret_cast<ushort4*>(dst + (size_t)row * DIM)[l] = o;
}

// Per-wave barrier-free GEMM. Wave tile 64x64, K-chunk 16, ring-4 per-wave LDS.
// Chunk layout (2KB = 128 x 16B granules): granule L holds global (r, g):
//   q=L>>5, m=(L>>1)&15, r=q*16+m, g=(L&1)^(q&1)^((m>>2)&1)^((m>>3)&1)
// (g = 16B half of the 32B row). 32 consecutive rows at fixed g -> 32 distinct
// granules mod 32, and distinct mod 8/16 within 8/16-lane subgroups (bank-clean).
__global__ __launch_bounds__(256) void gemm_kernel(
        const unsigned short* __restrict__ aB,
        const unsigned short* __restrict__ bB,
        const float* __restrict__ na,
        const float* __restrict__ nb,
        float* __restrict__ out) {
    __shared__ unsigned short sA[4][4][1024];  // [wave][ring slot][2KB chunk]
    __shared__ unsigned short sB[4][4][1024];
    __shared__ float sN[4][64];                // per-wave row norms (fixed rows)

    const int t = threadIdx.x;
    const int w = t >> 6, l = t & 63;
    const int hi = l >> 5, lr = l & 31, m4 = l & 3;

    const int gw = (int)blockIdx.x * 4 + w;    // 2048 waves
    const int row0 = (gw & 127) * 64;          // fixed row panel per wave
    const int col00 = (gw >> 7) * 64;          // tile ti: col0 = col00 + ti*1024

    // staging source pre-swizzle: instr i covers granules G = i*64 + l
    int rSt[2], gSt[2];
#pragma unroll
    for (int i = 0; i < 2; ++i) {
        const int G = i * 64 + l;
        const int q = G >> 5, m = (G >> 1) & 15;
        rSt[i] = q * 16 + m;
        gSt[i] = ((G & 1) ^ (q & 1) ^ ((m >> 2) & 1) ^ ((m >> 3) & 1)) * 8;
    }
    // fragment read byte offsets (A and B share the same formula)
    int offA[2];
#pragma unroll
    for (int mi = 0; mi < 2; ++mi) {
        const int r = mi * 32 + lr;
        const int q = r >> 4, m = r & 15;
        const int p = hi ^ (q & 1) ^ ((m >> 2) & 1) ^ ((m >> 3) & 1);
        offA[mi] = (q * 32 + m * 2 + p) * 16;
    }

    // prologue: row norms once; chunks 0,1,2 of tile 0
    GLDS(na + row0 + l, &sN[w][0], 4);
#pragma unroll
    for (int c = 0; c < 3; ++c) {
#pragma unroll
        for (int i = 0; i < 2; ++i)
            GLDS(aB + (size_t)(row0 + rSt[i]) * DIM + c * 16 + gSt[i],
                 &sA[w][c][i * 512], 16);
#pragma unroll
        for (int i = 0; i < 2; ++i)
            GLDS(bB + (size_t)(col00 + rSt[i]) * DIM + c * 16 + gSt[i],
                 &sB[w][c][i * 512], 16);
    }

    for (int ti = 0; ti < 8; ++ti) {
        const int col0 = col00 + ti * 1024;
        const float nbv0 = nb[col0 + lr];
        const float nbv1 = nb[col0 + 32 + lr];

        f32x16 acc[2][2];
#pragma unroll
        for (int mi = 0; mi < 2; ++mi)
#pragma unroll
            for (int ni = 0; ni < 2; ++ni) acc[mi][ni] = (f32x16)0.0f;

#pragma unroll
        for (int c = 0; c < 16; ++c) {
            // counted waits: N <= younger-LOADS-only (correct under any
            // store-retirement semantics). Steady lead = 2 chunks + nb loads.
            if (c <= 1)       { WAITV(10); }
            else if (c == 14) { if (ti == 7) { WAITV(4); } else { WAITV(8); } }
            else if (c == 15) { if (ti == 7) { WAITV(0); } else { WAITV(8); } }
            else              { WAITV(8); }

            // stage chunk c+3 (ring slot (c+3)&3; for c>=13 it's next tile's B)
            if (c < 13 || ti < 7) {
                const int sc = (c + 3) & 15;
                const int slot = (c + 3) & 3;
                const int colS = (c >= 13) ? col0 + 1024 : col0;
#pragma unroll
                for (int i = 0; i < 2; ++i)
                    GLDS(aB + (size_t)(row0 + rSt[i]) * DIM + sc * 16 + gSt[i],
                         &sA[w][slot][i * 512], 16);
#pragma unroll
                for (int i = 0; i < 2; ++i)
                    GLDS(bB + (size_t)(colS + rSt[i]) * DIM + sc * 16 + gSt[i],
                         &sB[w][slot][i * 512], 16);
            }

            // compute chunk c (slot c&3): 4 ds_read_b128 + 4 MFMA 32x32x16
            const int sl = c & 3;
            const bf16x8 a0 = *(const bf16x8*)((const char*)&sA[w][sl][0] + offA[0]);
            const bf16x8 a1 = *(const bf16x8*)((const char*)&sA[w][sl][0] + offA[1]);
            const bf16x8 b0 = *(const bf16x8*)((const char*)&sB[w][sl][0] + offA[0]);
            const bf16x8 b1 = *(const bf16x8*)((const char*)&sB[w][sl][0] + offA[1]);
            acc[0][0] = __builtin_amdgcn_mfma_f32_32x32x16_bf16(a0, b0, acc[0][0], 0, 0, 0);
            acc[0][1] = __builtin_amdgcn_mfma_f32_32x32x16_bf16(a0, b1, acc[0][1], 0, 0, 0);
            acc[1][0] = __builtin_amdgcn_mfma_f32_32x32x16_bf16(a1, b0, acc[1][0], 0, 0, 0);
            acc[1][1] = __builtin_amdgcn_mfma_f32_32x32x16_bf16(a1, b1, acc[1][1], 0, 0, 0);
        }

        // epilogue: exp + 4x4 lane transpose + 16 dwordx4 stores (R7-verified)
        const int colT = col0 + (lr >> 2) * 4;
#pragma unroll
        for (int ni = 0; ni < 2; ++ni) {
            const float nbv = ni ? nbv1 : nbv0;
#pragma unroll
            for (int mi = 0; mi < 2; ++mi) {
#pragma unroll
                for (int p = 0; p < 4; ++p) {
                    const f32x4 nv = *(const f32x4*)&sN[w][mi * 32 + 8 * p + 4 * hi];
                    float av[4];
#pragma unroll
                    for (int q = 0; q < 4; ++q) {
                        const float dot = acc[mi][ni][p * 4 + q];
                        const float sq = nv[q] + nbv - 2.0f * dot;
                        av[q] = 0.5f * __expf(-sq) + 0.5f * dot;
                    }
                    float tv;
                    tv = __shfl_xor((m4 & 1) ? av[0] : av[1], 1);
                    if (m4 & 1) av[0] = tv; else av[1] = tv;
                    tv = __shfl_xor((m4 & 1) ? av[2] : av[3], 1);
                    if (m4 & 1) av[2] = tv; else av[3] = tv;
                    tv = __shfl_xor((m4 & 2) ? av[0] : av[2], 2);
                    if (m4 & 2) av[0] = tv; else av[2] = tv;
                    tv = __shfl_xor((m4 & 2) ? av[1] : av[3], 2);
                    if (m4 & 2) av[1] = tv; else av[3] = tv;
                    const int row = row0 + mi * 32 + 8 * p + 4 * hi + m4;
                    f32x4 st; st[0] = av[0]; st[1] = av[1]; st[2] = av[2]; st[3] = av[3];
                    *(f32x4*)&out[(size_t)row * 8192 + colT + ni * 32] = st;
                }
            }
        }
    }
}

// Fallback if workspace is too small: fully naive f32 (correct, slow).
__global__ void naive_kernel(const float* __restrict__ a,
                             const float* __restrict__ b,
                             float* __restrict__ out) {
    const size_t idx = (size_t)blockIdx.x * 256 + threadIdx.x;
    const int i = (int)(idx >> 13);
    const int j = (int)(idx & 8191);
    float dot = 0.f, naa = 0.f, nbb = 0.f;
    for (int k = 0; k < DIM; ++k) {
        const float x = a[(size_t)i * DIM + k];
        const float y = b[(size_t)j * DIM + k];
        dot += x * y; naa += x * x; nbb += y * y;
    }
    const float sq = naa + nbb - 2.0f * dot;
    out[idx] = 0.5f * __expf(-sq) + 0.5f * dot;
}

extern "C" void kernel_launch(void* const* d_in, const int* in_sizes, int n_in,
                              void* d_out, int out_size, void* d_ws, size_t ws_size,
                              hipStream_t stream) {
    const float* a = (const float*)d_in[0];
    const float* b = (const float*)d_in[1];
    // d_in[2]=Wq, d_in[3]=Wk unused: softmax over a 1x1 score == 1 exactly,
    // so attn_sim == a.b and the projections cancel.
    float* out = (float*)d_out;

    const size_t bf_bytes = (size_t)NR * DIM * sizeof(unsigned short);
    const size_t nrm_bytes = (size_t)NR * sizeof(float);
    const size_t need = 2 * bf_bytes + 2 * nrm_bytes;

    if (ws_size >= need) {
        unsigned short* aBf = (unsigned short*)d_ws;
        unsigned short* bBf = (unsigned short*)((char*)d_ws + bf_bytes);
        float* na = (float*)((char*)d_ws + 2 * bf_bytes);
        float* nb = (float*)((char*)d_ws + 2 * bf_bytes + nrm_bytes);

        prep_kernel<<<4096, 256, 0, stream>>>(a, b, aBf, bBf, na, nb);
        gemm_kernel<<<512, 256, 0, stream>>>(aBf, bBf, na, nb, out);
    } else {
        naive_kernel<<<((size_t)NR * NR) / 256, 256, 0, stream>>>(a, b, out);
    }
}

// Round 10
// 92.718 us; speedup vs baseline: 1.4422x; 1.4422x over previous
//
#include <hip/hip_runtime.h>
#include <stdint.h>

#define DIM 256
#define NR 8192

typedef __bf16 bf16x8 __attribute__((ext_vector_type(8)));
typedef float  f32x16 __attribute__((ext_vector_type(16)));
typedef float  f32x4  __attribute__((ext_vector_type(4)));

#define MEMFENCE asm volatile("" ::: "memory")
#define WAITV(N) asm volatile("s_waitcnt vmcnt(" #N ")" ::: "memory")
#define BAR __builtin_amdgcn_s_barrier()
#define GLDS(src, dst, sz) __builtin_amdgcn_global_load_lds( \
    (const __attribute__((address_space(1))) void*)(src),    \
    (__attribute__((address_space(3))) void*)(dst), sz, 0, 0)

__device__ __forceinline__ unsigned short f2bf_rne(float f) {
    unsigned int u = __float_as_uint(f);
    u += 0x7FFFu + ((u >> 16) & 1u);
    return (unsigned short)(u >> 16);
}

// One wave per row: f32 row -> bf16 + ||row||^2. Blocks [0,2048)->a, rest->b.
__global__ void prep_kernel(const float* __restrict__ a,
                            const float* __restrict__ b,
                            unsigned short* __restrict__ aB,
                            unsigned short* __restrict__ bB,
                            float* __restrict__ na,
                            float* __restrict__ nb) {
    const int w = threadIdx.x >> 6;
    const int l = threadIdx.x & 63;
    const int blk = blockIdx.x;
    const float* src; unsigned short* dst; float* nrm; int row;
    if (blk < 2048) { src = a; dst = aB; nrm = na; row = blk * 4 + w; }
    else            { src = b; dst = bB; nrm = nb; row = (blk - 2048) * 4 + w; }
    const float4 v = reinterpret_cast<const float4*>(src + (size_t)row * DIM)[l];
    float ss = v.x * v.x + v.y * v.y + v.z * v.z + v.w * v.w;
#pragma unroll
    for (int off = 32; off > 0; off >>= 1) ss += __shfl_down(ss, off);
    if (l == 0) nrm[row] = ss;
    ushort4 o = make_ushort4(f2bf_rne(v.x), f2bf_rne(v.y), f2bf_rne(v.z), f2bf_rne(v.w));
    reinterpret_cast<ushort4*>(dst + (size_t)row * DIM)[l] = o;
}

// 32KB K-chunk buffer (256 rows x 64 K bf16), R5/R6-verified swizzle
// (SQ_LDS_BANK_CONFLICT == 0): LDS granule G holds global
// (r = 2*(G>>4) + (((G&15)^((G>>4)&15))>>3), c16 = ((G&15)^((G>>4)&15))&7).
// Read inverse: byte = (r>>1)*256 + ((((r&1)*8|hi)^((r>>1)&15)^(ks<<1))<<4).

// Stage A K-chunk kt_ of this block's 256-row panel into sA[buf_].
#define STAGE_A(kt_, buf_)                                                       \
    do {                                                                         \
        _Pragma("unroll")                                                        \
        for (int i_ = 0; i_ < 4; ++i_)                                           \
            GLDS(aB + (size_t)(row0 + rowSt[i_]) * DIM + (kt_) * 64 + colSt[i_], \
                 &sA[buf_][(w * 4 + i_) * 512], 16);                             \
    } while (0)

// Stage B K-chunk kt_ for col tile tc_ (256 cols) into sB[buf_].
#define STAGE_B(tc_, kt_, buf_)                                                  \
    do {                                                                         \
        _Pragma("unroll")                                                        \
        for (int i_ = 0; i_ < 4; ++i_)                                           \
            GLDS(bB + (size_t)(colSlab + (tc_) * 256 + rowSt[i_]) * DIM +        \
                     (kt_) * 64 + colSt[i_],                                     \
                 &sB[buf_][(w * 4 + i_) * 512], 16);                             \
    } while (0)

// One BK=64 phase: 4 ksteps x (4 A-frags, 2 B-frags, 8 MFMA 32x32x16).
#define COMPUTE(buf_)                                                            \
    do {                                                                         \
        __builtin_amdgcn_s_setprio(1);                                           \
        _Pragma("unroll")                                                        \
        for (int ks_ = 0; ks_ < 4; ++ks_) {                                      \
            bf16x8 af[4], bf[2];                                                 \
            _Pragma("unroll")                                                    \
            for (int mi_ = 0; mi_ < 4; ++mi_)                                    \
                af[mi_] = *(const bf16x8*)((const char*)&sA[buf_][0] +           \
                    baseA[mi_] + (((ks_ << 1) ^ XA[mi_]) << 4));                 \
            _Pragma("unroll")                                                    \
            for (int ni_ = 0; ni_ < 2; ++ni_)                                    \
                bf[ni_] = *(const bf16x8*)((const char*)&sB[buf_][0] +           \
                    baseB[ni_] + (((ks_ << 1) ^ XB[ni_]) << 4));                 \
            _Pragma("unroll")                                                    \
            for (int mi_ = 0; mi_ < 4; ++mi_)                                    \
                _Pragma("unroll")                                                \
                for (int ni_ = 0; ni_ < 2; ++ni_)                                \
                    acc[mi_][ni_] = __builtin_amdgcn_mfma_f32_32x32x16_bf16(     \
                        af[mi_], bf[ni_], acc[mi_][ni_], 0, 0, 0);               \
        }                                                                        \
        __builtin_amdgcn_s_setprio(0);                                           \
    } while (0)

__global__ __launch_bounds__(512, 1) void gemm_kernel(
        const unsigned short* __restrict__ aB,
        const unsigned short* __restrict__ bB,
        const float* __restrict__ na,
        const float* __restrict__ nb,
        float* __restrict__ out) {
    __shared__ unsigned short sA[2][16384];  // 2 x 32KB: A k-chunk dbuf
    __shared__ unsigned short sB[2][16384];  // 2 x 32KB: B k-chunk dbuf
    __shared__ float sN[256];                // panel row norms, resident

    const int t = threadIdx.x;
    const int w = t >> 6, l = t & 63;
    const int wr = w >> 2, wc = w & 3;       // 2x4 wave grid, wave tile 128x64
    const int hi = l >> 5, lr = l & 31, m4 = l & 3;

    // bid%8 -> XCD (round-robin dispatch): all 32 blocks of an XCD share one
    // 1024-col B slab (512KB, L2-resident) and walk aligned col tiles.
    const int slab = (int)blockIdx.x & 7;
    const int row0 = ((int)blockIdx.x >> 3) * 256;
    const int colSlab = slab * 1024;

    // staging source pre-swizzle: instr i covers granules G = (w*4+i)*64 + l
    int rowSt[4], colSt[4];
#pragma unroll
    for (int i = 0; i < 4; ++i) {
        const int G = (w * 4 + i) * 64 + l;
        const int rp = G >> 4, pos = G & 15;
        const int c2 = pos ^ (rp & 15);
        rowSt[i] = 2 * rp + (c2 >> 3);       // 0..255
        colSt[i] = (c2 & 7) * 8;             // ushort offset within 64-elem row
    }
    // fragment read bases
    int baseA[4], XA[4], baseB[2], XB[2];
#pragma unroll
    for (int mi = 0; mi < 4; ++mi) {
        const int r = wr * 128 + mi * 32 + lr;
        baseA[mi] = (r >> 1) * 256;
        XA[mi] = (((r & 1) * 8) | hi) ^ ((r >> 1) & 15);
    }
#pragma unroll
    for (int ni = 0; ni < 2; ++ni) {
        const int rb = wc * 64 + ni * 32 + lr;
        baseB[ni] = (rb >> 1) * 256;
        XB[ni] = (((rb & 1) * 8) | hi) ^ ((rb >> 1) & 15);
    }

    // ---- prologue: norms (waves 0-3), tile0 k0/k1, tile0 nb ----
    if (w < 4) GLDS(na + row0 + w * 64 + l, &sN[w * 64], 4);
    STAGE_A(0, 0); STAGE_B(0, 0, 0);     // 8 loads (k0)
    STAGE_A(1, 1); STAGE_B(0, 1, 1);     // 8 loads (k1)
    float nbv[2], nbN[2];
#pragma unroll
    for (int ni = 0; ni < 2; ++ni)
        nbv[ni] = nb[colSlab + wc * 64 + ni * 32 + lr];   // 2 loads
    MEMFENCE;

    f32x16 acc[4][2];

    for (int ti = 0; ti < 4; ++ti) {
        // ---- P0: compute k0 (buf0) ----
        if (ti == 0) { WAITV(10); } else { WAITV(42); }
        BAR; MEMFENCE;
        // acc init: compiler inserts the store-reg-reuse wait here (E-burst
        // of prev tile); L2 write queue absorbs it.
#pragma unroll
        for (int mi = 0; mi < 4; ++mi)
#pragma unroll
            for (int ni = 0; ni < 2; ++ni) acc[mi][ni] = (f32x16)0.0f;
        COMPUTE(0);
        MEMFENCE; BAR; MEMFENCE;
        STAGE_A(2, 0); STAGE_B(ti, 2, 0);
        MEMFENCE;

        // ---- P1: compute k1 (buf1) ----
        if (ti == 0) { WAITV(10); } else { WAITV(40); }
        BAR; MEMFENCE;
        COMPUTE(1);
        MEMFENCE; BAR; MEMFENCE;
        STAGE_A(3, 1); STAGE_B(ti, 3, 1);
        MEMFENCE;

        // ---- P2: compute k2 (buf0) ----
        WAITV(8);
        BAR; MEMFENCE;
        COMPUTE(0);
        MEMFENCE; BAR; MEMFENCE;
        if (ti < 3) {
            STAGE_A(0, 0); STAGE_B(ti + 1, 0, 0);
#pragma unroll
            for (int ni = 0; ni < 2; ++ni)
                nbN[ni] = nb[colSlab + (ti + 1) * 256 + wc * 64 + ni * 32 + lr];
        }
        MEMFENCE;

        // ---- P3: compute k3 (buf1) ----
        if (ti < 3) { WAITV(10); } else { WAITV(0); }
        BAR; MEMFENCE;
        COMPUTE(1);
        MEMFENCE; BAR; MEMFENCE;
        if (ti < 3) { STAGE_A(1, 1); STAGE_B(ti + 1, 1, 1); }
        MEMFENCE;

        // ---- E: epilogue in place + 32 dwordx4 stores (1KB/row bursts) ----
        const int col0 = colSlab + ti * 256;
        const int colT = col0 + wc * 64 + (lr >> 2) * 4;
#pragma unroll
        for (int mi = 0; mi < 4; ++mi) {
#pragma unroll
            for (int ni = 0; ni < 2; ++ni) {
#pragma unroll
                for (int p = 0; p < 4; ++p) {
                    const f32x4 nv = *(const f32x4*)&sN[wr * 128 + mi * 32 + 8 * p + 4 * hi];
                    float av[4];
#pragma unroll
                    for (int q = 0; q < 4; ++q) {
                        const float dot = acc[mi][ni][p * 4 + q];
                        const float sq = nv[q] + nbv[ni] - 2.0f * dot;
                        av[q] = 0.5f * __expf(-sq) + 0.5f * dot;
                    }
                    float tv;
                    tv = __shfl_xor((m4 & 1) ? av[0] : av[1], 1);
                    if (m4 & 1) av[0] = tv; else av[1] = tv;
                    tv = __shfl_xor((m4 & 1) ? av[2] : av[3], 1);
                    if (m4 & 1) av[2] = tv; else av[3] = tv;
                    tv = __shfl_xor((m4 & 2) ? av[0] : av[2], 2);
                    if (m4 & 2) av[0] = tv; else av[2] = tv;
                    tv = __shfl_xor((m4 & 2) ? av[1] : av[3], 2);
                    if (m4 & 2) av[1] = tv; else av[3] = tv;
                    const int row = row0 + wr * 128 + mi * 32 + 8 * p + 4 * hi + m4;
                    f32x4 st; st[0] = av[0]; st[1] = av[1]; st[2] = av[2]; st[3] = av[3];
                    *(f32x4*)&out[(size_t)row * 8192 + colT + ni * 32] = st;
                }
            }
        }
        nbv[0] = nbN[0]; nbv[1] = nbN[1];
        MEMFENCE;
    }
}

// Fallback if workspace is too small: fully naive f32 (correct, slow).
__global__ void naive_kernel(const float* __restrict__ a,
                             const float* __restrict__ b,
                             float* __restrict__ out) {
    const size_t idx = (size_t)blockIdx.x * 256 + threadIdx.x;
    const int i = (int)(idx >> 13);
    const int j = (int)(idx & 8191);
    float dot = 0.f, naa = 0.f, nbb = 0.f;
    for (int k = 0; k < DIM; ++k) {
        const float x = a[(size_t)i * DIM + k];
        const float y = b[(size_t)j * DIM + k];
        dot += x * y; naa += x * x; nbb += y * y;
    }
    const float sq = naa + nbb - 2.0f * dot;
    out[idx] = 0.5f * __expf(-sq) + 0.5f * dot;
}

extern "C" void kernel_launch(void* const* d_in, const int* in_sizes, int n_in,
                              void* d_out, int out_size, void* d_ws, size_t ws_size,
                              hipStream_t stream) {
    const float* a = (const float*)d_in[0];
    const float* b = (const float*)d_in[1];
    // d_in[2]=Wq, d_in[3]=Wk unused: softmax over a 1x1 score == 1 exactly,
    // so attn_sim == a.b and the projections cancel.
    float* out = (float*)d_out;

    const size_t bf_bytes = (size_t)NR * DIM * sizeof(unsigned short);
    const size_t nrm_bytes = (size_t)NR * sizeof(float);
    const size_t need = 2 * bf_bytes + 2 * nrm_bytes;

    if (ws_size >= need) {
        unsigned short* aBf = (unsigned short*)d_ws;
        unsigned short* bBf = (unsigned short*)((char*)d_ws + bf_bytes);
        float* na = (float*)((char*)d_ws + 2 * bf_bytes);
        float* nb = (float*)((char*)d_ws + 2 * bf_bytes + nrm_bytes);

        prep_kernel<<<4096, 256, 0, stream>>>(a, b, aBf, bBf, na, nb);
        gemm_kernel<<<256, 512, 0, stream>>>(aBf, bBf, na, nb, out);
    } else {
        naive_kernel<<<((size_t)NR * NR) / 256, 256, 0, stream>>>(a, b, out);
    }
}

// Round 11
// 85.870 us; speedup vs baseline: 1.5572x; 1.0797x over previous
//
#include <hip/hip_runtime.h>
#include <stdint.h>

#define DIM 256
#define NR 8192

typedef __bf16 bf16x8 __attribute__((ext_vector_type(8)));
typedef float  f32x16 __attribute__((ext_vector_type(16)));
typedef float  f32x4  __attribute__((ext_vector_type(4)));

#define MEMFENCE asm volatile("" ::: "memory")
#define WAITV(N) asm volatile("s_waitcnt vmcnt(" #N ")" ::: "memory")
#define BAR __builtin_amdgcn_s_barrier()
#define GLDS(src, dst, sz) __builtin_amdgcn_global_load_lds( \
    (const __attribute__((address_space(1))) void*)(src),    \
    (__attribute__((address_space(3))) void*)(dst), sz, 0, 0)

__device__ __forceinline__ unsigned short f2bf_rne(float f) {
    unsigned int u = __float_as_uint(f);
    u += 0x7FFFu + ((u >> 16) & 1u);
    return (unsigned short)(u >> 16);
}

// ---- prep v2: emit fragment-ordered 64-row panels + norms ----
// A panel p (64 rows x 256 k), ushort layout:
//   (mi*16+ks)*512 + (hi*32 + lr)*8 + half*4   (mi=row>>5, lr=row&31,
//    k = ks*16 + hi*8 + half*4 + 0..3)  -> gemm A-load instr (mi,ks) reads
//   512 contiguous ushorts, lane l takes l*8.
// B panel: ks*1024 + ni*512 + hi*256 + lc*8 + half*4 (ni=col>>5, lc=col&31)
//   -> LDS-linear staging, frag read (ks,ni): byte ks*2048+ni*1024+hi*512+lr*16.
__global__ void prep_kernel(const float* __restrict__ a,
                            const float* __restrict__ b,
                            unsigned short* __restrict__ aF,
                            unsigned short* __restrict__ bF,
                            float* __restrict__ na,
                            float* __restrict__ nb) {
    __shared__ unsigned short sP[16384];   // 32KB panel image
    const int t = threadIdx.x;
    const int w = t >> 6, l = t & 63;
    const int pb = blockIdx.x;
    const int isA = pb < 128;
    const int p = isA ? pb : pb - 128;
    const float* src = isA ? a : b;
    float* nrm = isA ? na : nb;

    const int ks = l >> 2, hi2 = (l >> 1) & 1, half = l & 1;
    for (int i = 0; i < 16; ++i) {
        const int rp = i * 4 + w;              // row within panel
        const int row = p * 64 + rp;
        const float4 v = reinterpret_cast<const float4*>(src + (size_t)row * DIM)[l];
        float ss = v.x * v.x + v.y * v.y + v.z * v.z + v.w * v.w;
#pragma unroll
        for (int off = 32; off > 0; off >>= 1) ss += __shfl_down(ss, off);
        if (l == 0) nrm[row] = ss;
        uint2 pk;
        pk.x = (unsigned)f2bf_rne(v.x) | ((unsigned)f2bf_rne(v.y) << 16);
        pk.y = (unsigned)f2bf_rne(v.z) | ((unsigned)f2bf_rne(v.w) << 16);
        int idx;
        if (isA) { const int mi = rp >> 5, lr2 = rp & 31;
            idx = (mi * 16 + ks) * 512 + (hi2 * 32 + lr2) * 8 + half * 4; }
        else     { const int ni = rp >> 5, lc = rp & 31;
            idx = ks * 1024 + ni * 512 + hi2 * 256 + lc * 8 + half * 4; }
        *(uint2*)&sP[idx] = pk;
    }
    __syncthreads();
    unsigned short* dst = (isA ? aF : bF) + (size_t)p * 16384;
#pragma unroll
    for (int i = 0; i < 8; ++i)
        *(uint4*)&dst[t * 64 + i * 8] = *(uint4*)&sP[t * 64 + i * 8];
}

// Stage B job jj (64 cols) + its nb slice into buffer bb: 5 loads per wave.
#define STAGE_B(jj, bb)                                                          \
    do {                                                                         \
        const int pc_ = cr * 8 + (jj);                                           \
        _Pragma("unroll")                                                        \
        for (int i_ = 0; i_ < 4; ++i_)                                           \
            GLDS(bF + (size_t)pc_ * 16384 + (w * 4 + i_) * 512 + l * 8,          \
                 &sB[bb][(w * 4 + i_) * 512], 16);                               \
        GLDS(nbF + cr * 512 + (jj) * 64 + l, &sNB[bb][0], 4);                    \
    } while (0)

__global__ __launch_bounds__(512, 2) void gemm_kernel(
        const unsigned short* __restrict__ aF,
        const unsigned short* __restrict__ bF,
        const float* __restrict__ naF,
        const float* __restrict__ nbF,
        float* __restrict__ out) {
    __shared__ unsigned short sB[2][16384];   // B job dbuf, 32KB each
    __shared__ float sN[512];                 // block row norms
    __shared__ float sNB[2][64];              // job col norms

    const int t = threadIdx.x;
    const int w = t >> 6, l = t & 63;
    const int hi = l >> 5, lr = l & 31, m4 = l & 3;

    const int cr = (int)blockIdx.x & 15;      // 512-col range (XCD-paired)
    const int pg = (int)blockIdx.x >> 4;      // 512-row group
    const int rows0 = pg * 512;
    const int col0b = cr * 512;
    const int pA = pg * 8 + w;                // wave's 64-row A panel

    // ---- A panel -> 128 VGPRs (32 contiguous 1KB loads, once) ----
    bf16x8 af[2][16];
#pragma unroll
    for (int mi = 0; mi < 2; ++mi)
#pragma unroll
        for (int ks = 0; ks < 16; ++ks)
            af[mi][ks] = *(const bf16x8*)&aF[(size_t)(pA * 32 + mi * 16 + ks) * 512 + l * 8];

    GLDS(naF + rows0 + w * 64 + l, &sN[w * 64], 4);
    STAGE_B(0, 0);
    STAGE_B(1, 1);
    MEMFENCE;

    float na_s[2][4];
    for (int j = 0; j < 8; ++j) {
        if (j < 7) { WAITV(5); } else { WAITV(0); }
        BAR; MEMFENCE;
        if (j == 0) {
#pragma unroll
            for (int mi = 0; mi < 2; ++mi)
#pragma unroll
                for (int pp = 0; pp < 4; ++pp)
                    na_s[mi][pp] = sN[w * 64 + mi * 32 + pp * 8 + 4 * hi + m4];
        }

        f32x16 acc[2][2];
#pragma unroll
        for (int mi = 0; mi < 2; ++mi)
#pragma unroll
            for (int ni = 0; ni < 2; ++ni) acc[mi][ni] = (f32x16)0.0f;

        const char* bbase = (const char*)&sB[j & 1][0];
        __builtin_amdgcn_s_setprio(1);
#pragma unroll
        for (int ks = 0; ks < 16; ++ks) {
            const bf16x8 b0 = *(const bf16x8*)(bbase + ks * 2048 + hi * 512 + lr * 16);
            const bf16x8 b1 = *(const bf16x8*)(bbase + ks * 2048 + 1024 + hi * 512 + lr * 16);
            acc[0][0] = __builtin_amdgcn_mfma_f32_32x32x16_bf16(af[0][ks], b0, acc[0][0], 0, 0, 0);
            acc[1][0] = __builtin_amdgcn_mfma_f32_32x32x16_bf16(af[1][ks], b0, acc[1][0], 0, 0, 0);
            acc[0][1] = __builtin_amdgcn_mfma_f32_32x32x16_bf16(af[0][ks], b1, acc[0][1], 0, 0, 0);
            acc[1][1] = __builtin_amdgcn_mfma_f32_32x32x16_bf16(af[1][ks], b1, acc[1][1], 0, 0, 0);
        }
        __builtin_amdgcn_s_setprio(0);

        // ---- epilogue: transpose (verified) + formula + cached f32x4 stores ----
        const int c0 = (lr >> 2) * 4;
        const f32x4 nbv0 = *(const f32x4*)&sNB[j & 1][c0];
        const f32x4 nbv1 = *(const f32x4*)&sNB[j & 1][32 + c0];
        const int col0 = col0b + j * 64;
#pragma unroll
        for (int mi = 0; mi < 2; ++mi) {
#pragma unroll
            for (int ni = 0; ni < 2; ++ni) {
                const f32x4 nbq = ni ? nbv1 : nbv0;
#pragma unroll
                for (int pp = 0; pp < 4; ++pp) {
                    float av[4];
#pragma unroll
                    for (int q = 0; q < 4; ++q) av[q] = acc[mi][ni][pp * 4 + q];
                    float tv;
                    tv = __shfl_xor((m4 & 1) ? av[0] : av[1], 1);
                    if (m4 & 1) av[0] = tv; else av[1] = tv;
                    tv = __shfl_xor((m4 & 1) ? av[2] : av[3], 1);
                    if (m4 & 1) av[2] = tv; else av[3] = tv;
                    tv = __shfl_xor((m4 & 2) ? av[0] : av[2], 2);
                    if (m4 & 2) av[0] = tv; else av[2] = tv;
                    tv = __shfl_xor((m4 & 2) ? av[1] : av[3], 2);
                    if (m4 & 2) av[1] = tv; else av[3] = tv;
                    const float nas = na_s[mi][pp];
                    f32x4 st;
#pragma unroll
                    for (int q = 0; q < 4; ++q) {
                        const float d = av[q];
                        const float sq = nas + nbq[q] - 2.0f * d;
                        st[q] = 0.5f * __expf(-sq) + 0.5f * d;
                    }
                    const int row = rows0 + w * 64 + mi * 32 + pp * 8 + 4 * hi + m4;
                    *(f32x4*)&out[(size_t)row * 8192 + col0 + ni * 32 + c0] = st;
                }
            }
        }
        MEMFENCE; BAR; MEMFENCE;
        if (j < 6) STAGE_B(j + 2, j & 1);
        MEMFENCE;
    }
}

// Fallback if workspace is too small: fully naive f32 (correct, slow).
__global__ void naive_kernel(const float* __restrict__ a,
                             const float* __restrict__ b,
                             float* __restrict__ out) {
    const size_t idx = (size_t)blockIdx.x * 256 + threadIdx.x;
    const int i = (int)(idx >> 13);
    const int j = (int)(idx & 8191);
    float dot = 0.f, naa = 0.f, nbb = 0.f;
    for (int k = 0; k < DIM; ++k) {
        const float x = a[(size_t)i * DIM + k];
        const float y = b[(size_t)j * DIM + k];
        dot += x * y; naa += x * x; nbb += y * y;
    }
    const float sq = naa + nbb - 2.0f * dot;
    out[idx] = 0.5f * __expf(-sq) + 0.5f * dot;
}

extern "C" void kernel_launch(void* const* d_in, const int* in_sizes, int n_in,
                              void* d_out, int out_size, void* d_ws, size_t ws_size,
                              hipStream_t stream) {
    const float* a = (const float*)d_in[0];
    const float* b = (const float*)d_in[1];
    // d_in[2]=Wq, d_in[3]=Wk unused: softmax over a 1x1 score == 1 exactly,
    // so attn_sim == a.b and the projections cancel.
    float* out = (float*)d_out;

    const size_t bf_bytes = (size_t)NR * DIM * sizeof(unsigned short); // 4MB
    const size_t nrm_bytes = (size_t)NR * sizeof(float);               // 32KB
    const size_t need = 2 * bf_bytes + 2 * nrm_bytes;

    if (ws_size >= need) {
        unsigned short* aF = (unsigned short*)d_ws;
        unsigned short* bF = (unsigned short*)((char*)d_ws + bf_bytes);
        float* na = (float*)((char*)d_ws + 2 * bf_bytes);
        float* nb = (float*)((char*)d_ws + 2 * bf_bytes + nrm_bytes);

        prep_kernel<<<256, 256, 0, stream>>>(a, b, aF, bF, na, nb);
        gemm_kernel<<<256, 512, 0, stream>>>(aF, bF, na, nb, out);
    } else {
        naive_kernel<<<((size_t)NR * NR) / 256, 256, 0, stream>>>(a, b, out);
    }
}